// Round 18
// baseline (697.914 us; speedup 1.0000x reference)
//
#include <hip/hip_runtime.h>
#include <cstdint>

#define NN 50000
#define NE 800000

using u16 = unsigned short;
using bf16x8 = __attribute__((ext_vector_type(8))) short;
using f32x4  = __attribute__((ext_vector_type(4))) float;

// ---- workspace layout (float-offset units) ----
static constexpr long long OFF_E    = 0;          // e (bf16, CSR-permuted order) [E,64]
static constexpr long long OFF_H    = 25600000;   // h  [N,64] f32
static constexpr long long OFF_R    = 28800000;   // r  [N,64] f32
static constexpr long long OFF_AG   = 32000000;   // aggr [N,64] f32 ; t1/t2 overlay after convs
static constexpr long long OFF_CSR  = 35200000;   // CSR ints below
static constexpr long long OFF_ST   = 41600000;   // stats 1024 floats
static constexpr size_t    WS_NEED  = (size_t)(OFF_ST + 1024) * 4;  // 166.4 MB

// CSR sub-layout (int offsets relative to OFF_CSR; region spans 6.4M ints)
static constexpr long long CSR_ROWPTR = 0;         // [N+1]
static constexpr long long CSR_CNT    = 50004;     // [N]
static constexpr long long CSR_PERM   = 100096;    // [E]
static constexpr long long CSR_SSRC   = 900096;    // [E]
static constexpr long long CSR_BSUM   = 1900000;   // [64] block sums for scan
static constexpr long long CSR_WT     = 2000000;   // bf16 Wt [64][64]
static constexpr long long CSR_SPART  = 3000000;   // f32 BN partials [2048][128] (1 MB)

// bf16 <-> f32 (RNE)
__device__ __forceinline__ float bf2f(u16 u){ return __uint_as_float(((unsigned)u) << 16); }
__device__ __forceinline__ u16 f2bf(float f){
    unsigned u = __float_as_uint(f);
    return (u16)((u + 0x7FFFu + ((u >> 16) & 1u)) >> 16);
}

// ---------- encoder layer 1 (persistent grid-stride): out = A[rows,K] @ W[K,64] + b ----------
template<int K, bool BF>
__global__ __launch_bounds__(256) void enc1_kernel(
    const float* __restrict__ A, const float* __restrict__ W,
    const float* __restrict__ bias, void* __restrict__ outv,
    const int* __restrict__ permOpt,
    float* __restrict__ stPart, int rows, int tiles)
{
    __shared__ __align__(16) float At[64][K + 4];
    __shared__ __align__(16) float Wl[K][64];
    __shared__ float ssum[64], ssq[64];
    const int tid = threadIdx.x;
    for (int i = tid; i < K * 64; i += 256) Wl[i >> 6][i & 63] = W[i];
    if (tid < 64) { ssum[tid] = 0.f; ssq[tid] = 0.f; }
    const int tx = tid & 15, ty = tid >> 4;
    const float4 bv = *(const float4*)&bias[tx * 4];
    float cs[4] = {0.f,0.f,0.f,0.f}, cq[4] = {0.f,0.f,0.f,0.f};
    constexpr int KC = K / 4;
    __syncthreads();

    for (int tile = blockIdx.x; tile < tiles; tile += gridDim.x){
        const int base = tile * 64;
        for (int i4 = tid; i4 < 64 * KC; i4 += 256){
            int r = i4 / KC, kc = i4 - r * KC;
            int gr = base + r;
            float4 v = {0.f, 0.f, 0.f, 0.f};
            if (gr < rows){
                int orig = permOpt ? permOpt[gr] : gr;
                v = *(const float4*)&A[(long long)orig * K + kc * 4];
            }
            *(float4*)&At[r][kc * 4] = v;
        }
        __syncthreads();
        float acc[4][4];
        #pragma unroll
        for (int i = 0; i < 4; i++){ acc[i][0]=0.f; acc[i][1]=0.f; acc[i][2]=0.f; acc[i][3]=0.f; }
        #pragma unroll
        for (int k4 = 0; k4 < KC; k4++){
            float4 b0 = *(const float4*)&Wl[k4 * 4 + 0][tx * 4];
            float4 b1 = *(const float4*)&Wl[k4 * 4 + 1][tx * 4];
            float4 b2 = *(const float4*)&Wl[k4 * 4 + 2][tx * 4];
            float4 b3 = *(const float4*)&Wl[k4 * 4 + 3][tx * 4];
            #pragma unroll
            for (int i = 0; i < 4; i++){
                float4 a = *(const float4*)&At[ty * 4 + i][k4 * 4];
                acc[i][0] = fmaf(a.x, b0.x, acc[i][0]); acc[i][1] = fmaf(a.x, b0.y, acc[i][1]);
                acc[i][2] = fmaf(a.x, b0.z, acc[i][2]); acc[i][3] = fmaf(a.x, b0.w, acc[i][3]);
                acc[i][0] = fmaf(a.y, b1.x, acc[i][0]); acc[i][1] = fmaf(a.y, b1.y, acc[i][1]);
                acc[i][2] = fmaf(a.y, b1.z, acc[i][2]); acc[i][3] = fmaf(a.y, b1.w, acc[i][3]);
                acc[i][0] = fmaf(a.z, b2.x, acc[i][0]); acc[i][1] = fmaf(a.z, b2.y, acc[i][1]);
                acc[i][2] = fmaf(a.z, b2.z, acc[i][2]); acc[i][3] = fmaf(a.z, b2.w, acc[i][3]);
                acc[i][0] = fmaf(a.w, b3.x, acc[i][0]); acc[i][1] = fmaf(a.w, b3.y, acc[i][1]);
                acc[i][2] = fmaf(a.w, b3.z, acc[i][2]); acc[i][3] = fmaf(a.w, b3.w, acc[i][3]);
            }
        }
        #pragma unroll
        for (int i = 0; i < 4; i++){
            int gr = base + ty * 4 + i;
            if (gr < rows){
                float4 o;
                o.x = acc[i][0] + bv.x; o.y = acc[i][1] + bv.y;
                o.z = acc[i][2] + bv.z; o.w = acc[i][3] + bv.w;
                if (BF){
                    ushort4 s;
                    s.x = f2bf(o.x); s.y = f2bf(o.y); s.z = f2bf(o.z); s.w = f2bf(o.w);
                    *(ushort4*)((u16*)outv + (long long)gr * 64 + tx * 4) = s;
                } else {
                    *(float4*)((float*)outv + (long long)gr * 64 + tx * 4) = o;
                }
                cs[0]+=o.x; cs[1]+=o.y; cs[2]+=o.z; cs[3]+=o.w;
                cq[0]+=o.x*o.x; cq[1]+=o.y*o.y; cq[2]+=o.z*o.z; cq[3]+=o.w*o.w;
            }
        }
        __syncthreads();
    }
    #pragma unroll
    for (int j = 0; j < 4; j++){
        atomicAdd(&ssum[tx * 4 + j], cs[j]);
        atomicAdd(&ssq [tx * 4 + j], cq[j]);
    }
    __syncthreads();
    if (tid < 64){
        stPart[(long long)blockIdx.x * 128 + tid]      = ssum[tid];
        stPart[(long long)blockIdx.x * 128 + 64 + tid] = ssq[tid];
    }
}

// ---------- parallel reduce of BN partials ----------
__global__ __launch_bounds__(128) void stat_reduce_par(
    const float* __restrict__ part, int nb,
    float* __restrict__ sum, float* __restrict__ sq)
{
    int t = threadIdx.x;
    int b0 = blockIdx.x * 16;
    float s = 0.f;
    #pragma unroll
    for (int j = 0; j < 16; j++){
        int b = b0 + j;
        if (b < nb) s += part[(long long)b * 128 + t];
    }
    if (t < 64) atomicAdd(&sum[t], s);
    else        atomicAdd(&sq[t - 64], s);
}

// ---------- finalize BN ----------
__global__ void bn_finalize(const float* __restrict__ sum, const float* __restrict__ sq,
                            const float* __restrict__ g, const float* __restrict__ B,
                            float* __restrict__ scale, float* __restrict__ shift,
                            float invCount, int CO)
{
    int t = threadIdx.x;
    if (t < CO){
        float mu = sum[t] * invCount;
        float var = fmaf(-mu, mu, sq[t] * invCount);
        float sc = g[t] * rsqrtf(var + 1e-5f);
        scale[t] = sc;
        shift[t] = fmaf(-mu, sc, B[t]);
    }
}

// ---------- encoder layer 2 (fp32, 64 rows/block — NODE encoder) ----------
template<bool BF>
__global__ __launch_bounds__(256) void enc2_kernel(
    void* __restrict__ iov, const float* __restrict__ W, const float* __restrict__ bias,
    const float* __restrict__ scale, const float* __restrict__ shift, int rows)
{
    __shared__ __align__(16) float At[64][68];
    __shared__ __align__(16) float Wl[64][64];
    const int tid = threadIdx.x;
    const int base = blockIdx.x * 64;
    for (int i = tid; i < 4096; i += 256) Wl[i >> 6][i & 63] = W[i];
    for (int i4 = tid; i4 < 1024; i4 += 256){
        int r = i4 >> 4, kc = i4 & 15;
        int gr = base + r;
        float4 v = {0.f, 0.f, 0.f, 0.f};
        if (gr < rows){
            if (BF){
                ushort4 s = *(const ushort4*)((const u16*)iov + (long long)gr * 64 + kc * 4);
                v.x = bf2f(s.x); v.y = bf2f(s.y); v.z = bf2f(s.z); v.w = bf2f(s.w);
            } else {
                v = *(const float4*)((const float*)iov + (long long)gr * 64 + kc * 4);
            }
        }
        float4 o;
        o.x = fmaxf(fmaf(v.x, scale[kc*4+0], shift[kc*4+0]), 0.f);
        o.y = fmaxf(fmaf(v.y, scale[kc*4+1], shift[kc*4+1]), 0.f);
        o.z = fmaxf(fmaf(v.z, scale[kc*4+2], shift[kc*4+2]), 0.f);
        o.w = fmaxf(fmaf(v.w, scale[kc*4+3], shift[kc*4+3]), 0.f);
        *(float4*)&At[r][kc * 4] = o;
    }
    __syncthreads();
    const int tx = tid & 15, ty = tid >> 4;
    float acc[4][4];
    #pragma unroll
    for (int i = 0; i < 4; i++){ acc[i][0]=0.f; acc[i][1]=0.f; acc[i][2]=0.f; acc[i][3]=0.f; }
    #pragma unroll 4
    for (int k4 = 0; k4 < 16; k4++){
        float4 b0 = *(const float4*)&Wl[k4 * 4 + 0][tx * 4];
        float4 b1 = *(const float4*)&Wl[k4 * 4 + 1][tx * 4];
        float4 b2 = *(const float4*)&Wl[k4 * 4 + 2][tx * 4];
        float4 b3 = *(const float4*)&Wl[k4 * 4 + 3][tx * 4];
        #pragma unroll
        for (int i = 0; i < 4; i++){
            float4 a = *(const float4*)&At[ty * 4 + i][k4 * 4];
            acc[i][0] = fmaf(a.x, b0.x, acc[i][0]); acc[i][1] = fmaf(a.x, b0.y, acc[i][1]);
            acc[i][2] = fmaf(a.x, b0.z, acc[i][2]); acc[i][3] = fmaf(a.x, b0.w, acc[i][3]);
            acc[i][0] = fmaf(a.y, b1.x, acc[i][0]); acc[i][1] = fmaf(a.y, b1.y, acc[i][1]);
            acc[i][2] = fmaf(a.y, b1.z, acc[i][2]); acc[i][3] = fmaf(a.y, b1.w, acc[i][3]);
            acc[i][0] = fmaf(a.z, b2.x, acc[i][0]); acc[i][1] = fmaf(a.z, b2.y, acc[i][1]);
            acc[i][2] = fmaf(a.z, b2.z, acc[i][2]); acc[i][3] = fmaf(a.z, b2.w, acc[i][3]);
            acc[i][0] = fmaf(a.w, b3.x, acc[i][0]); acc[i][1] = fmaf(a.w, b3.y, acc[i][1]);
            acc[i][2] = fmaf(a.w, b3.z, acc[i][2]); acc[i][3] = fmaf(a.w, b3.w, acc[i][3]);
        }
    }
    float4 bv = *(const float4*)&bias[tx * 4];
    #pragma unroll
    for (int i = 0; i < 4; i++){
        int gr = base + ty * 4 + i;
        if (gr < rows){
            float4 o;
            o.x = acc[i][0] + bv.x; o.y = acc[i][1] + bv.y;
            o.z = acc[i][2] + bv.z; o.w = acc[i][3] + bv.w;
            if (BF){
                ushort4 s;
                s.x = f2bf(o.x); s.y = f2bf(o.y); s.z = f2bf(o.z); s.w = f2bf(o.w);
                *(ushort4*)((u16*)iov + (long long)gr * 64 + tx * 4) = s;
            } else {
                *(float4*)((float*)iov + (long long)gr * 64 + tx * 4) = o;
            }
        }
    }
}

// ---------- Wt prep ----------
__global__ void wt_prep_kernel(const float* __restrict__ W, u16* __restrict__ wt)
{
    int i = blockIdx.x * 256 + threadIdx.x;
    if (i < 4096){ int k = i >> 6, c = i & 63; wt[c * 64 + k] = f2bf(W[i]); }
}

// ---------- EDGE encoder layer 2 via MFMA (in-place on bf16 e) ----------
__global__ __launch_bounds__(256) void enc2_mfma_kernel(
    u16* __restrict__ e, const u16* __restrict__ wt, const float* __restrict__ bias,
    const float* __restrict__ scale, const float* __restrict__ shift)
{
    __shared__ __align__(16) u16 At[64][72];
    __shared__ __align__(16) u16 Wt[64][72];
    const int tid = threadIdx.x;
    const long long base = (long long)blockIdx.x * 64;
    for (int i = tid; i < 1024; i += 256){
        int c = i >> 4, kc = i & 15;
        *(ushort4*)&Wt[c][kc * 4] = *(const ushort4*)&wt[c * 64 + kc * 4];
    }
    for (int i = tid; i < 1024; i += 256){
        int r = i >> 4, kc = i & 15;
        ushort4 s = *(const ushort4*)&e[(base + r) * 64 + kc * 4];
        float v0 = fmaxf(fmaf(bf2f(s.x), scale[kc*4+0], shift[kc*4+0]), 0.f);
        float v1 = fmaxf(fmaf(bf2f(s.y), scale[kc*4+1], shift[kc*4+1]), 0.f);
        float v2 = fmaxf(fmaf(bf2f(s.z), scale[kc*4+2], shift[kc*4+2]), 0.f);
        float v3 = fmaxf(fmaf(bf2f(s.w), scale[kc*4+3], shift[kc*4+3]), 0.f);
        ushort4 o; o.x = f2bf(v0); o.y = f2bf(v1); o.z = f2bf(v2); o.w = f2bf(v3);
        *(ushort4*)&At[r][kc * 4] = o;
    }
    __syncthreads();
    const int l = tid & 63;
    const int r0 = (tid >> 6) * 16;
    const int lr = l & 15, lk = (l >> 4) * 8;
    f32x4 acc0 = {0.f,0.f,0.f,0.f}, acc1 = {0.f,0.f,0.f,0.f};
    f32x4 acc2 = {0.f,0.f,0.f,0.f}, acc3 = {0.f,0.f,0.f,0.f};
    #pragma unroll
    for (int k0 = 0; k0 < 64; k0 += 32){
        bf16x8 a  = *(const bf16x8*)&At[r0 + lr][k0 + lk];
        bf16x8 b0 = *(const bf16x8*)&Wt[ 0 + lr][k0 + lk];
        bf16x8 b1 = *(const bf16x8*)&Wt[16 + lr][k0 + lk];
        bf16x8 b2 = *(const bf16x8*)&Wt[32 + lr][k0 + lk];
        bf16x8 b3 = *(const bf16x8*)&Wt[48 + lr][k0 + lk];
        acc0 = __builtin_amdgcn_mfma_f32_16x16x32_bf16(a, b0, acc0, 0, 0, 0);
        acc1 = __builtin_amdgcn_mfma_f32_16x16x32_bf16(a, b1, acc1, 0, 0, 0);
        acc2 = __builtin_amdgcn_mfma_f32_16x16x32_bf16(a, b2, acc2, 0, 0, 0);
        acc3 = __builtin_amdgcn_mfma_f32_16x16x32_bf16(a, b3, acc3, 0, 0, 0);
    }
    const int orow = r0 + (l >> 4) * 4;
    const float bb0 = bias[ 0 + lr], bb1 = bias[16 + lr];
    const float bb2 = bias[32 + lr], bb3 = bias[48 + lr];
    #pragma unroll
    for (int r = 0; r < 4; r++){
        long long rb = (base + orow + r) * 64;
        e[rb +  0 + lr] = f2bf(acc0[r] + bb0);
        e[rb + 16 + lr] = f2bf(acc1[r] + bb1);
        e[rb + 32 + lr] = f2bf(acc2[r] + bb2);
        e[rb + 48 + lr] = f2bf(acc3[r] + bb3);
    }
}

// ---------- r = relu(LayerNorm(h)) ----------
__global__ __launch_bounds__(256) void ln_relu_kernel(
    const float* __restrict__ h, float* __restrict__ r,
    const float* __restrict__ g, const float* __restrict__ b, int rows)
{
    int tid = blockIdx.x * 256 + threadIdx.x;
    int row = tid >> 4, fc = tid & 15;
    if (row >= rows) return;
    float4 v = *(const float4*)&h[(long long)row * 64 + fc * 4];
    float s = v.x + v.y + v.z + v.w;
    float q = v.x*v.x + v.y*v.y + v.z*v.z + v.w*v.w;
    #pragma unroll
    for (int m = 1; m < 16; m <<= 1){ s += __shfl_xor(s, m, 64); q += __shfl_xor(q, m, 64); }
    float mu = s * (1.f / 64.f);
    float var = fmaf(-mu, mu, q * (1.f / 64.f));
    float rs = rsqrtf(var + 1e-5f);
    float4 gv = *(const float4*)&g[fc * 4];
    float4 bv = *(const float4*)&b[fc * 4];
    float4 o;
    o.x = fmaxf(fmaf((v.x - mu) * rs, gv.x, bv.x), 0.f);
    o.y = fmaxf(fmaf((v.y - mu) * rs, gv.y, bv.y), 0.f);
    o.z = fmaxf(fmaf((v.z - mu) * rs, gv.z, bv.z), 0.f);
    o.w = fmaxf(fmaf((v.w - mu) * rs, gv.w, bv.w), 0.f);
    *(float4*)&r[(long long)row * 64 + fc * 4] = o;
}

// ---------- CSR build ----------
__global__ __launch_bounds__(256) void hist_kernel(
    const int* __restrict__ dst, int* __restrict__ cnt)
{
    int eidx = blockIdx.x * 256 + threadIdx.x;
    if (eidx < NE) atomicAdd(&cnt[dst[eidx]], 1);
}

__global__ __launch_bounds__(1024) void scan1_kernel(
    const int* __restrict__ cnt, int* __restrict__ rowptr, int* __restrict__ bsum, int n)
{
    __shared__ int buf[1024];
    int tid = threadIdx.x;
    int gid = blockIdx.x * 1024 + tid;
    int v = (gid < n) ? cnt[gid] : 0;
    buf[tid] = v;
    __syncthreads();
    for (int off = 1; off < 1024; off <<= 1){
        int add = (tid >= off) ? buf[tid - off] : 0;
        __syncthreads();
        buf[tid] += add;
        __syncthreads();
    }
    if (gid < n) rowptr[gid] = buf[tid] - v;
    if (tid == 1023) bsum[blockIdx.x] = buf[1023];
}

__global__ void scan2_kernel(int* __restrict__ bsum, int B)
{
    int lane = threadIdx.x;
    int v = (lane < B) ? bsum[lane] : 0;
    int orig = v;
    #pragma unroll
    for (int off = 1; off < 64; off <<= 1){
        int u = __shfl_up(v, off, 64);
        if (lane >= off) v += u;
    }
    if (lane < B) bsum[lane] = v - orig;
}

__global__ __launch_bounds__(1024) void scan3_kernel(
    int* __restrict__ rowptr, const int* __restrict__ bsum, int n)
{
    int gid = blockIdx.x * 1024 + threadIdx.x;
    if (gid < n) rowptr[gid] += bsum[blockIdx.x];
    if (gid == 0) rowptr[n] = NE;
}

__global__ __launch_bounds__(256) void scatter_kernel(
    const int* __restrict__ src, const int* __restrict__ dst,
    int* __restrict__ cursor, int* __restrict__ perm, int* __restrict__ ssrc)
{
    int eidx = blockIdx.x * 256 + threadIdx.x;
    if (eidx >= NE) return;
    int pos = atomicAdd(&cursor[dst[eidx]], 1);
    perm[pos] = eidx;
    ssrc[pos] = src[eidx];
}

// ---------- per-node aggregation: one wave per node, lane = feature ----------
// No max-tracking: softmax is shift-invariant and inputs are bounded
// (msg = relu(.)+1e-7 <= ~20 => exp2(tl*msg) <= ~5e8, den <= deg*5e8 << FLT_MAX),
// so w = exp2(tl*msg) directly == exp(t*msg). Removes the serial m/rescale chain.
__global__ __launch_bounds__(256) void aggr_kernel(
    const u16* __restrict__ e, const float* __restrict__ xn,
    const int* __restrict__ ssrc,
    const int* __restrict__ rowptr, float* __restrict__ aggr,
    const float* __restrict__ tptr, int rows)
{
    int node = (blockIdx.x * 256 + threadIdx.x) >> 6;
    int lane = threadIdx.x & 63;
    if (node >= rows) return;
    const float tl = (*tptr) * 1.44269504088896f;   // t * log2(e)
    int beg = rowptr[node], end = rowptr[node + 1];
    float den = 0.f, num = 0.f;
    int i = beg;
    for (; i + 4 <= end; i += 4){
        float ev0 = bf2f(e[(long long)(i + 0) * 64 + lane]);
        float ev1 = bf2f(e[(long long)(i + 1) * 64 + lane]);
        float ev2 = bf2f(e[(long long)(i + 2) * 64 + lane]);
        float ev3 = bf2f(e[(long long)(i + 3) * 64 + lane]);
        int s0 = ssrc[i + 0], s1 = ssrc[i + 1], s2 = ssrc[i + 2], s3 = ssrc[i + 3];
        float xv0 = xn[(long long)s0 * 64 + lane];
        float xv1 = xn[(long long)s1 * 64 + lane];
        float xv2 = xn[(long long)s2 * 64 + lane];
        float xv3 = xn[(long long)s3 * 64 + lane];
        float msg0 = fmaxf(xv0 + ev0, 0.f) + 1e-7f;
        float msg1 = fmaxf(xv1 + ev1, 0.f) + 1e-7f;
        float msg2 = fmaxf(xv2 + ev2, 0.f) + 1e-7f;
        float msg3 = fmaxf(xv3 + ev3, 0.f) + 1e-7f;
        float w0 = exp2f(tl * msg0);
        float w1 = exp2f(tl * msg1);
        float w2 = exp2f(tl * msg2);
        float w3 = exp2f(tl * msg3);
        den += (w0 + w1) + (w2 + w3);
        num += fmaf(msg0, w0, msg1 * w1) + fmaf(msg2, w2, msg3 * w3);
    }
    for (; i < end; ++i){
        float ev = bf2f(e[(long long)i * 64 + lane]);
        int s = ssrc[i];
        float xv = xn[(long long)s * 64 + lane];
        float msg = fmaxf(xv + ev, 0.f) + 1e-7f;
        float w = exp2f(tl * msg);
        den += w;
        num = fmaf(msg, w, num);
    }
    aggr[(long long)node * 64 + lane] = num / (den + 1e-16f);
}

// ---------- conv node update: a = aggr+rin; h(+)= relu(LN(a@W1+b1))@W2+b2 ----------
__global__ __launch_bounds__(256) void conv_mlp_kernel(
    const float* __restrict__ rin, const float* __restrict__ aggr,
    float* __restrict__ h,
    const float* __restrict__ W1, const float* __restrict__ b1,
    const float* __restrict__ g, const float* __restrict__ B,
    const float* __restrict__ W2, const float* __restrict__ b2,
    int addToH, int rows)
{
    __shared__ __align__(16) float At[32][68];
    __shared__ __align__(16) float Wl[8192];
    __shared__ __align__(16) float Hs[32][132];
    __shared__ float lred[64];
    __shared__ float lmu[32], lrs[32];
    const int tid = threadIdx.x;
    const int base = blockIdx.x * 32;
    for (int i = tid; i < 8192; i += 256) Wl[i] = W1[i];
    for (int i4 = tid; i4 < 512; i4 += 256){
        int r = i4 >> 4, kc = i4 & 15;
        int gr = base + r;
        float4 v = {0.f, 0.f, 0.f, 0.f};
        if (gr < rows){
            long long idx = (long long)gr * 64 + kc * 4;
            float4 av = *(const float4*)&aggr[idx];
            float4 rv = *(const float4*)&rin[idx];
            v.x = av.x + rv.x; v.y = av.y + rv.y; v.z = av.z + rv.z; v.w = av.w + rv.w;
        }
        *(float4*)&At[r][kc * 4] = v;
    }
    if (tid < 64) lred[tid] = 0.f;
    __syncthreads();
    // GEMM1: [32,64] @ [64,128]  (float4 along k)
    {
        const int tx = tid & 31, ty = tid >> 5;
        float acc[4][4];
        #pragma unroll
        for (int i = 0; i < 4; i++){ acc[i][0]=0.f; acc[i][1]=0.f; acc[i][2]=0.f; acc[i][3]=0.f; }
        #pragma unroll 4
        for (int k4 = 0; k4 < 16; k4++){
            float4 b0 = *(const float4*)&Wl[(k4 * 4 + 0) * 128 + tx * 4];
            float4 b1 = *(const float4*)&Wl[(k4 * 4 + 1) * 128 + tx * 4];
            float4 b2 = *(const float4*)&Wl[(k4 * 4 + 2) * 128 + tx * 4];
            float4 b3 = *(const float4*)&Wl[(k4 * 4 + 3) * 128 + tx * 4];
            #pragma unroll
            for (int i = 0; i < 4; i++){
                float4 a = *(const float4*)&At[ty * 4 + i][k4 * 4];
                acc[i][0] = fmaf(a.x, b0.x, acc[i][0]); acc[i][1] = fmaf(a.x, b0.y, acc[i][1]);
                acc[i][2] = fmaf(a.x, b0.z, acc[i][2]); acc[i][3] = fmaf(a.x, b0.w, acc[i][3]);
                acc[i][0] = fmaf(a.y, b1.x, acc[i][0]); acc[i][1] = fmaf(a.y, b1.y, acc[i][1]);
                acc[i][2] = fmaf(a.y, b1.z, acc[i][2]); acc[i][3] = fmaf(a.y, b1.w, acc[i][3]);
                acc[i][0] = fmaf(a.z, b2.x, acc[i][0]); acc[i][1] = fmaf(a.z, b2.y, acc[i][1]);
                acc[i][2] = fmaf(a.z, b2.z, acc[i][2]); acc[i][3] = fmaf(a.z, b2.w, acc[i][3]);
                acc[i][0] = fmaf(a.w, b3.x, acc[i][0]); acc[i][1] = fmaf(a.w, b3.y, acc[i][1]);
                acc[i][2] = fmaf(a.w, b3.z, acc[i][2]); acc[i][3] = fmaf(a.w, b3.w, acc[i][3]);
            }
        }
        float4 bv = *(const float4*)&b1[tx * 4];
        #pragma unroll
        for (int i = 0; i < 4; i++){
            float4 o;
            o.x = acc[i][0] + bv.x; o.y = acc[i][1] + bv.y;
            o.z = acc[i][2] + bv.z; o.w = acc[i][3] + bv.w;
            *(float4*)&Hs[ty * 4 + i][tx * 4] = o;
        }
    }
    __syncthreads();
    // LN stats over 128 per row
    {
        int row = tid & 31, seg = tid >> 5;
        float s = 0.f, q = 0.f;
        #pragma unroll
        for (int j = 0; j < 16; j++){
            float v = Hs[row][seg * 16 + j];
            s += v; q = fmaf(v, v, q);
        }
        atomicAdd(&lred[row], s);
        atomicAdd(&lred[32 + row], q);
    }
    __syncthreads();
    if (tid < 32){
        float mu = lred[tid] * (1.f / 128.f);
        float var = fmaf(-mu, mu, lred[32 + tid] * (1.f / 128.f));
        lmu[tid] = mu; lrs[tid] = rsqrtf(var + 1e-5f);
    }
    __syncthreads();
    for (int i = tid; i < 4096; i += 256){
        int row = i >> 7, k = i & 127;
        float v = Hs[row][k];
        v = fmaf((v - lmu[row]) * lrs[row], g[k], B[k]);
        Hs[row][k] = fmaxf(v, 0.f);
    }
    __syncthreads();
    for (int i = tid; i < 8192; i += 256) Wl[i] = W2[i];
    __syncthreads();
    // GEMM2: [32,128] @ [128,64] (+ residual into h)  (float4 along k)
    {
        const int tx = tid & 15, ty = tid >> 4;
        float acc[2][4];
        #pragma unroll
        for (int i = 0; i < 2; i++){ acc[i][0]=0.f; acc[i][1]=0.f; acc[i][2]=0.f; acc[i][3]=0.f; }
        #pragma unroll 4
        for (int k4 = 0; k4 < 32; k4++){
            float4 b0 = *(const float4*)&Wl[(k4 * 4 + 0) * 64 + tx * 4];
            float4 b1 = *(const float4*)&Wl[(k4 * 4 + 1) * 64 + tx * 4];
            float4 b2 = *(const float4*)&Wl[(k4 * 4 + 2) * 64 + tx * 4];
            float4 b3 = *(const float4*)&Wl[(k4 * 4 + 3) * 64 + tx * 4];
            #pragma unroll
            for (int i = 0; i < 2; i++){
                float4 a = *(const float4*)&Hs[ty * 2 + i][k4 * 4];
                acc[i][0] = fmaf(a.x, b0.x, acc[i][0]); acc[i][1] = fmaf(a.x, b0.y, acc[i][1]);
                acc[i][2] = fmaf(a.x, b0.z, acc[i][2]); acc[i][3] = fmaf(a.x, b0.w, acc[i][3]);
                acc[i][0] = fmaf(a.y, b1.x, acc[i][0]); acc[i][1] = fmaf(a.y, b1.y, acc[i][1]);
                acc[i][2] = fmaf(a.y, b1.z, acc[i][2]); acc[i][3] = fmaf(a.y, b1.w, acc[i][3]);
                acc[i][0] = fmaf(a.z, b2.x, acc[i][0]); acc[i][1] = fmaf(a.z, b2.y, acc[i][1]);
                acc[i][2] = fmaf(a.z, b2.z, acc[i][2]); acc[i][3] = fmaf(a.z, b2.w, acc[i][3]);
                acc[i][0] = fmaf(a.w, b3.x, acc[i][0]); acc[i][1] = fmaf(a.w, b3.y, acc[i][1]);
                acc[i][2] = fmaf(a.w, b3.z, acc[i][2]); acc[i][3] = fmaf(a.w, b3.w, acc[i][3]);
            }
        }
        float4 bv = *(const float4*)&b2[tx * 4];
        #pragma unroll
        for (int i = 0; i < 2; i++){
            int gr = base + ty * 2 + i;
            if (gr < rows){
                float4 o;
                o.x = acc[i][0] + bv.x; o.y = acc[i][1] + bv.y;
                o.z = acc[i][2] + bv.z; o.w = acc[i][3] + bv.w;
                long long idx = (long long)gr * 64 + tx * 4;
                if (addToH){
                    float4 c = *(const float4*)&h[idx];
                    o.x += c.x; o.y += c.y; o.z += c.z; o.w += c.w;
                }
                *(float4*)&h[idx] = o;
            }
        }
    }
}

// ---------- out MLP stage 1: 64 rows/block, 4 lanes/row x 8 cols ----------
__global__ __launch_bounds__(256) void out1_kernel(
    const float* __restrict__ A, const float* __restrict__ W, const float* __restrict__ bias,
    float* __restrict__ out, float* __restrict__ stSum, float* __restrict__ stSq, int rows)
{
    __shared__ __align__(16) float At[64][68];
    __shared__ __align__(16) float Wl[64][32];
    __shared__ float ssum[32], ssq[32];
    const int tid = threadIdx.x;
    const int base = blockIdx.x * 64;
    for (int i = tid; i < 2048; i += 256) Wl[i >> 5][i & 31] = W[i];
    if (tid < 32){ ssum[tid] = 0.f; ssq[tid] = 0.f; }
    for (int i4 = tid; i4 < 1024; i4 += 256){
        int r = i4 >> 4, kc = i4 & 15;
        int gr = base + r;
        float4 v = {0.f, 0.f, 0.f, 0.f};
        if (gr < rows) v = *(const float4*)&A[(long long)gr * 64 + kc * 4];
        *(float4*)&At[r][kc * 4] = v;
    }
    __syncthreads();
    const int row = tid >> 2, lane = tid & 3;
    const int gr = base + row;
    float acc[8];
    #pragma unroll
    for (int j = 0; j < 8; j++) acc[j] = bias[lane * 8 + j];
    #pragma unroll 4
    for (int k4 = 0; k4 < 16; k4++){
        float4 a = *(const float4*)&At[row][k4 * 4];
        float av[4] = {a.x, a.y, a.z, a.w};
        #pragma unroll
        for (int j = 0; j < 4; j++){
            float4 w0 = *(const float4*)&Wl[k4 * 4 + j][lane * 8];
            float4 w1 = *(const float4*)&Wl[k4 * 4 + j][lane * 8 + 4];
            acc[0] = fmaf(av[j], w0.x, acc[0]); acc[1] = fmaf(av[j], w0.y, acc[1]);
            acc[2] = fmaf(av[j], w0.z, acc[2]); acc[3] = fmaf(av[j], w0.w, acc[3]);
            acc[4] = fmaf(av[j], w1.x, acc[4]); acc[5] = fmaf(av[j], w1.y, acc[5]);
            acc[6] = fmaf(av[j], w1.z, acc[6]); acc[7] = fmaf(av[j], w1.w, acc[7]);
        }
    }
    if (gr < rows){
        float4 o0 = {acc[0], acc[1], acc[2], acc[3]};
        float4 o1 = {acc[4], acc[5], acc[6], acc[7]};
        *(float4*)&out[(long long)gr * 32 + lane * 8]     = o0;
        *(float4*)&out[(long long)gr * 32 + lane * 8 + 4] = o1;
        #pragma unroll
        for (int j = 0; j < 8; j++){
            atomicAdd(&ssum[lane * 8 + j], acc[j]);
            atomicAdd(&ssq [lane * 8 + j], acc[j] * acc[j]);
        }
    }
    __syncthreads();
    if (tid < 32){ atomicAdd(&stSum[tid], ssum[tid]); atomicAdd(&stSq[tid], ssq[tid]); }
}

// ---------- out MLP stage 2: 64 rows/block, 4 lanes/row x 4 cols; BN applied at staging ----------
__global__ __launch_bounds__(256) void out2_kernel(
    const float* __restrict__ A, const float* __restrict__ W, const float* __restrict__ bias,
    float* __restrict__ out, const float* __restrict__ sc, const float* __restrict__ sh,
    float* __restrict__ stSum, float* __restrict__ stSq, int rows)
{
    __shared__ __align__(16) float At[64][36];
    __shared__ __align__(16) float Wl[32][16];
    __shared__ float ssum[16], ssq[16];
    const int tid = threadIdx.x;
    const int base = blockIdx.x * 64;
    for (int i = tid; i < 512; i += 256) Wl[i >> 4][i & 15] = W[i];
    if (tid < 16){ ssum[tid] = 0.f; ssq[tid] = 0.f; }
    for (int i4 = tid; i4 < 512; i4 += 256){
        int r = i4 >> 3, kc = i4 & 7;
        int gr = base + r;
        float4 v = {0.f, 0.f, 0.f, 0.f};
        if (gr < rows) v = *(const float4*)&A[(long long)gr * 32 + kc * 4];
        float4 o;
        o.x = fmaxf(fmaf(v.x, sc[kc*4+0], sh[kc*4+0]), 0.f);
        o.y = fmaxf(fmaf(v.y, sc[kc*4+1], sh[kc*4+1]), 0.f);
        o.z = fmaxf(fmaf(v.z, sc[kc*4+2], sh[kc*4+2]), 0.f);
        o.w = fmaxf(fmaf(v.w, sc[kc*4+3], sh[kc*4+3]), 0.f);
        *(float4*)&At[r][kc * 4] = o;
    }
    __syncthreads();
    const int row = tid >> 2, lane = tid & 3;
    const int gr = base + row;
    float acc[4];
    #pragma unroll
    for (int j = 0; j < 4; j++) acc[j] = bias[lane * 4 + j];
    #pragma unroll 2
    for (int k4 = 0; k4 < 8; k4++){
        float4 a = *(const float4*)&At[row][k4 * 4];
        float av[4] = {a.x, a.y, a.z, a.w};
        #pragma unroll
        for (int j = 0; j < 4; j++){
            float4 w = *(const float4*)&Wl[k4 * 4 + j][lane * 4];
            acc[0] = fmaf(av[j], w.x, acc[0]); acc[1] = fmaf(av[j], w.y, acc[1]);
            acc[2] = fmaf(av[j], w.z, acc[2]); acc[3] = fmaf(av[j], w.w, acc[3]);
        }
    }
    if (gr < rows){
        float4 o = {acc[0], acc[1], acc[2], acc[3]};
        *(float4*)&out[(long long)gr * 16 + lane * 4] = o;
        #pragma unroll
        for (int j = 0; j < 4; j++){
            atomicAdd(&ssum[lane * 4 + j], acc[j]);
            atomicAdd(&ssq [lane * 4 + j], acc[j] * acc[j]);
        }
    }
    __syncthreads();
    if (tid < 16){ atomicAdd(&stSum[tid], ssum[tid]); atomicAdd(&stSq[tid], ssq[tid]); }
}

// ---------- out MLP stage 3 ----------
__global__ __launch_bounds__(256) void out3_kernel(
    const float* __restrict__ A, const float* __restrict__ W, const float* __restrict__ bias,
    const float* __restrict__ sc, const float* __restrict__ sh,
    float* __restrict__ out, int rows)
{
    int row = blockIdx.x * 256 + threadIdx.x;
    if (row >= rows) return;
    float o0 = bias[0], o1 = bias[1];
    #pragma unroll
    for (int k = 0; k < 16; k++){
        float a = fmaxf(fmaf(A[(long long)row * 16 + k], sc[k], sh[k]), 0.f);
        o0 = fmaf(a, W[k * 2 + 0], o0);
        o1 = fmaf(a, W[k * 2 + 1], o1);
    }
    out[(long long)row * 2 + 0] = o0;
    out[(long long)row * 2 + 1] = o1;
}

extern "C" void kernel_launch(void* const* d_in, const int* in_sizes, int n_in,
                              void* d_out, int out_size, void* d_ws, size_t ws_size,
                              hipStream_t stream)
{
    (void)in_sizes; (void)n_in; (void)out_size;
    if (ws_size < WS_NEED) return;

    const float* x    = (const float*)d_in[0];
    const float* ea   = (const float*)d_in[1];
    const int*   eidx = (const int*)  d_in[2];
    const float* nW1  = (const float*)d_in[3];
    const float* nb1  = (const float*)d_in[4];
    const float* ng1  = (const float*)d_in[5];
    const float* nB1  = (const float*)d_in[6];
    const float* nW2  = (const float*)d_in[7];
    const float* nb2  = (const float*)d_in[8];
    const float* eW1  = (const float*)d_in[9];
    const float* eb1  = (const float*)d_in[10];
    const float* eg1  = (const float*)d_in[11];
    const float* eB1  = (const float*)d_in[12];
    const float* eW2  = (const float*)d_in[13];
    const float* eb2  = (const float*)d_in[14];
    const float* lng  = (const float*)d_in[15];
    const float* lnb  = (const float*)d_in[16];
    const float* cW1  = (const float*)d_in[17];
    const float* cb1  = (const float*)d_in[18];
    const float* cg   = (const float*)d_in[19];
    const float* cB   = (const float*)d_in[20];
    const float* cW2  = (const float*)d_in[21];
    const float* cb2  = (const float*)d_in[22];
    const float* ct   = (const float*)d_in[23];
    const float* oW1  = (const float*)d_in[24];
    const float* ob1  = (const float*)d_in[25];
    const float* og1  = (const float*)d_in[26];
    const float* oB1  = (const float*)d_in[27];
    const float* oW2  = (const float*)d_in[28];
    const float* ob2  = (const float*)d_in[29];
    const float* og2  = (const float*)d_in[30];
    const float* oB2  = (const float*)d_in[31];
    const float* oW3  = (const float*)d_in[32];
    const float* ob3  = (const float*)d_in[33];

    float* ws = (float*)d_ws;
    u16*   e    = (u16*)(ws + OFF_E);
    float* h    = ws + OFF_H;
    float* r    = ws + OFF_R;
    float* aggr = ws + OFF_AG;
    int*   csr  = (int*)(ws + OFF_CSR);
    int*   rowptr = csr + CSR_ROWPTR;
    int*   cnt    = csr + CSR_CNT;
    int*   perm   = csr + CSR_PERM;
    int*   ssrc   = csr + CSR_SSRC;
    int*   bsum   = csr + CSR_BSUM;
    u16*   wt     = (u16*)(csr + CSR_WT);
    float* stPart = (float*)(csr + CSR_SPART);
    float* t1   = ws + OFF_AG;                 // overlay (aggr dead after convs)
    float* t2   = ws + OFF_AG + 1600000;
    float* st   = ws + OFF_ST;
    float* sumA = st;        float* sqA = st + 128;
    float* scA  = st + 256;  float* shA = st + 384;
    float* sumB = st + 512;  float* sqB = st + 640;
    float* scB  = st + 768;  float* shB = st + 896;

    const int* src = eidx;
    const int* dst = eidx + NE;
    const int SCAN_B = (NN + 1023) / 1024;   // 49

    // ---- CSR build (once; depends only on edge_index) ----
    (void)hipMemsetAsync(cnt, 0, NN * sizeof(int), stream);
    hist_kernel<<<(NE + 255) / 256, 256, 0, stream>>>(dst, cnt);
    scan1_kernel<<<SCAN_B, 1024, 0, stream>>>(cnt, rowptr, bsum, NN);
    scan2_kernel<<<1, 64, 0, stream>>>(bsum, SCAN_B);
    scan3_kernel<<<SCAN_B, 1024, 0, stream>>>(rowptr, bsum, NN);
    (void)hipMemcpyAsync(cnt, rowptr, NN * sizeof(int), hipMemcpyDeviceToDevice, stream);
    scatter_kernel<<<(NE + 255) / 256, 256, 0, stream>>>(src, dst, cnt, perm, ssrc);
    wt_prep_kernel<<<16, 256, 0, stream>>>(eW2, wt);

    // ---- node encoder (fp32 h) ----
    (void)hipMemsetAsync(st, 0, 256 * sizeof(float), stream);
    enc1_kernel<16, false><<<1024, 256, 0, stream>>>(x, nW1, nb1, h, nullptr, stPart, NN, (NN + 63) / 64);
    stat_reduce_par<<<64, 128, 0, stream>>>(stPart, 1024, sumA, sqA);
    bn_finalize<<<1, 128, 0, stream>>>(sumA, sqA, ng1, nB1, scA, shA, 1.f / NN, 64);
    enc2_kernel<false><<<(NN + 63) / 64, 256, 0, stream>>>(h, nW2, nb2, scA, shA, NN);
    // ---- edge encoder (bf16 e in CSR-permuted order; layer 2 via MFMA) ----
    (void)hipMemsetAsync(st, 0, 256 * sizeof(float), stream);
    enc1_kernel<8, true><<<2048, 256, 0, stream>>>(ea, eW1, eb1, e, perm, stPart, NE, NE / 64);
    stat_reduce_par<<<128, 128, 0, stream>>>(stPart, 2048, sumA, sqA);
    bn_finalize<<<1, 128, 0, stream>>>(sumA, sqA, eg1, eB1, scA, shA, 1.f / NE, 64);
    enc2_mfma_kernel<<<NE / 64, 256, 0, stream>>>(e, wt, eb2, scA, shA);

    // ---- 4 GENConv layers ----
    for (int l = 0; l < 4; l++){
        const float* rin = (l == 0) ? h : r;
        if (l > 0)
            ln_relu_kernel<<<(NN * 16) / 256, 256, 0, stream>>>(h, r, lng + l * 64, lnb + l * 64, NN);
        aggr_kernel<<<(NN * 64 + 255) / 256, 256, 0, stream>>>(
            e, rin, ssrc, rowptr, aggr, ct + l, NN);
        conv_mlp_kernel<<<(NN + 31) / 32, 256, 0, stream>>>(
            rin, aggr, h,
            cW1 + (long long)l * 8192, cb1 + l * 128, cg + l * 128, cB + l * 128,
            cW2 + (long long)l * 8192, cb2 + l * 64, (l > 0) ? 1 : 0, NN);
    }

    // ---- out MLP ----
    (void)hipMemsetAsync(st, 0, 1024 * sizeof(float), stream);
    out1_kernel<<<(NN + 63) / 64, 256, 0, stream>>>(h, oW1, ob1, t1, sumA, sqA, NN);
    bn_finalize<<<1, 128, 0, stream>>>(sumA, sqA, og1, oB1, scA, shA, 1.f / NN, 32);
    out2_kernel<<<(NN + 63) / 64, 256, 0, stream>>>(t1, oW2, ob2, t2, scA, shA, sumB, sqB, NN);
    bn_finalize<<<1, 128, 0, stream>>>(sumB, sqB, og2, oB2, scB, shB, 1.f / NN, 16);
    out3_kernel<<<(NN + 255) / 256, 256, 0, stream>>>(t2, oW3, ob3, scB, shB, (float*)d_out, NN);
}

// Round 20
// 622.910 us; speedup vs baseline: 1.1204x; 1.1204x over previous
//
#include <hip/hip_runtime.h>
#include <cstdint>

#define NN 50000
#define NE 800000

using u16 = unsigned short;
using bf16x8 = __attribute__((ext_vector_type(8))) short;
using f32x4  = __attribute__((ext_vector_type(4))) float;

// ---- workspace layout (float-offset units) ----
static constexpr long long OFF_E    = 0;          // e (bf16, CSR-permuted order) [E,64]
static constexpr long long OFF_H    = 25600000;   // h  [N,64] f32
static constexpr long long OFF_R    = 28800000;   // r  [N,64] f32
static constexpr long long OFF_AG   = 32000000;   // aggr [N,64] f32 ; t1/t2 overlay after convs
static constexpr long long OFF_CSR  = 35200000;   // CSR ints below
static constexpr long long OFF_ST   = 41600000;   // stats 1024 floats
static constexpr size_t    WS_NEED  = (size_t)(OFF_ST + 1024) * 4;  // 166.4 MB

// CSR sub-layout (int offsets relative to OFF_CSR; region spans 6.4M ints)
static constexpr long long CSR_ROWPTR = 0;         // [N+1]
static constexpr long long CSR_CNT    = 50004;     // [N]
static constexpr long long CSR_PERM   = 100096;    // [E]
static constexpr long long CSR_SSRC   = 900096;    // [E]
static constexpr long long CSR_BSUM   = 1900000;   // [64] block sums for scan
static constexpr long long CSR_WT     = 2000000;   // bf16 Wt [64][64] (edge enc2)
static constexpr long long CSR_WT1    = 2100000;   // bf16 wt1 [L][128][64]  (16384 ints)
static constexpr long long CSR_WT2    = 2200000;   // bf16 wt2 [L][64][128]  (16384 ints)
static constexpr long long CSR_SPART  = 3000000;   // f32 BN partials [2048][128] (1 MB)

// bf16 <-> f32 (RNE)
__device__ __forceinline__ float bf2f(u16 u){ return __uint_as_float(((unsigned)u) << 16); }
__device__ __forceinline__ u16 f2bf(float f){
    unsigned u = __float_as_uint(f);
    return (u16)((u + 0x7FFFu + ((u >> 16) & 1u)) >> 16);
}

// ---------- encoder layer 1 (persistent grid-stride): out = A[rows,K] @ W[K,64] + b ----------
template<int K, bool BF>
__global__ __launch_bounds__(256) void enc1_kernel(
    const float* __restrict__ A, const float* __restrict__ W,
    const float* __restrict__ bias, void* __restrict__ outv,
    const int* __restrict__ permOpt,
    float* __restrict__ stPart, int rows, int tiles)
{
    __shared__ __align__(16) float At[64][K + 4];
    __shared__ __align__(16) float Wl[K][64];
    __shared__ float ssum[64], ssq[64];
    const int tid = threadIdx.x;
    for (int i = tid; i < K * 64; i += 256) Wl[i >> 6][i & 63] = W[i];
    if (tid < 64) { ssum[tid] = 0.f; ssq[tid] = 0.f; }
    const int tx = tid & 15, ty = tid >> 4;
    const float4 bv = *(const float4*)&bias[tx * 4];
    float cs[4] = {0.f,0.f,0.f,0.f}, cq[4] = {0.f,0.f,0.f,0.f};
    constexpr int KC = K / 4;
    __syncthreads();

    for (int tile = blockIdx.x; tile < tiles; tile += gridDim.x){
        const int base = tile * 64;
        for (int i4 = tid; i4 < 64 * KC; i4 += 256){
            int r = i4 / KC, kc = i4 - r * KC;
            int gr = base + r;
            float4 v = {0.f, 0.f, 0.f, 0.f};
            if (gr < rows){
                int orig = permOpt ? permOpt[gr] : gr;
                v = *(const float4*)&A[(long long)orig * K + kc * 4];
            }
            *(float4*)&At[r][kc * 4] = v;
        }
        __syncthreads();
        float acc[4][4];
        #pragma unroll
        for (int i = 0; i < 4; i++){ acc[i][0]=0.f; acc[i][1]=0.f; acc[i][2]=0.f; acc[i][3]=0.f; }
        #pragma unroll
        for (int k4 = 0; k4 < KC; k4++){
            float4 b0 = *(const float4*)&Wl[k4 * 4 + 0][tx * 4];
            float4 b1 = *(const float4*)&Wl[k4 * 4 + 1][tx * 4];
            float4 b2 = *(const float4*)&Wl[k4 * 4 + 2][tx * 4];
            float4 b3 = *(const float4*)&Wl[k4 * 4 + 3][tx * 4];
            #pragma unroll
            for (int i = 0; i < 4; i++){
                float4 a = *(const float4*)&At[ty * 4 + i][k4 * 4];
                acc[i][0] = fmaf(a.x, b0.x, acc[i][0]); acc[i][1] = fmaf(a.x, b0.y, acc[i][1]);
                acc[i][2] = fmaf(a.x, b0.z, acc[i][2]); acc[i][3] = fmaf(a.x, b0.w, acc[i][3]);
                acc[i][0] = fmaf(a.y, b1.x, acc[i][0]); acc[i][1] = fmaf(a.y, b1.y, acc[i][1]);
                acc[i][2] = fmaf(a.y, b1.z, acc[i][2]); acc[i][3] = fmaf(a.y, b1.w, acc[i][3]);
                acc[i][0] = fmaf(a.z, b2.x, acc[i][0]); acc[i][1] = fmaf(a.z, b2.y, acc[i][1]);
                acc[i][2] = fmaf(a.z, b2.z, acc[i][2]); acc[i][3] = fmaf(a.z, b2.w, acc[i][3]);
                acc[i][0] = fmaf(a.w, b3.x, acc[i][0]); acc[i][1] = fmaf(a.w, b3.y, acc[i][1]);
                acc[i][2] = fmaf(a.w, b3.z, acc[i][2]); acc[i][3] = fmaf(a.w, b3.w, acc[i][3]);
            }
        }
        #pragma unroll
        for (int i = 0; i < 4; i++){
            int gr = base + ty * 4 + i;
            if (gr < rows){
                float4 o;
                o.x = acc[i][0] + bv.x; o.y = acc[i][1] + bv.y;
                o.z = acc[i][2] + bv.z; o.w = acc[i][3] + bv.w;
                if (BF){
                    ushort4 s;
                    s.x = f2bf(o.x); s.y = f2bf(o.y); s.z = f2bf(o.z); s.w = f2bf(o.w);
                    *(ushort4*)((u16*)outv + (long long)gr * 64 + tx * 4) = s;
                } else {
                    *(float4*)((float*)outv + (long long)gr * 64 + tx * 4) = o;
                }
                cs[0]+=o.x; cs[1]+=o.y; cs[2]+=o.z; cs[3]+=o.w;
                cq[0]+=o.x*o.x; cq[1]+=o.y*o.y; cq[2]+=o.z*o.z; cq[3]+=o.w*o.w;
            }
        }
        __syncthreads();
    }
    #pragma unroll
    for (int j = 0; j < 4; j++){
        atomicAdd(&ssum[tx * 4 + j], cs[j]);
        atomicAdd(&ssq [tx * 4 + j], cq[j]);
    }
    __syncthreads();
    if (tid < 64){
        stPart[(long long)blockIdx.x * 128 + tid]      = ssum[tid];
        stPart[(long long)blockIdx.x * 128 + 64 + tid] = ssq[tid];
    }
}

// ---------- parallel reduce of BN partials ----------
__global__ __launch_bounds__(128) void stat_reduce_par(
    const float* __restrict__ part, int nb,
    float* __restrict__ sum, float* __restrict__ sq)
{
    int t = threadIdx.x;
    int b0 = blockIdx.x * 16;
    float s = 0.f;
    #pragma unroll
    for (int j = 0; j < 16; j++){
        int b = b0 + j;
        if (b < nb) s += part[(long long)b * 128 + t];
    }
    if (t < 64) atomicAdd(&sum[t], s);
    else        atomicAdd(&sq[t - 64], s);
}

// ---------- finalize BN ----------
__global__ void bn_finalize(const float* __restrict__ sum, const float* __restrict__ sq,
                            const float* __restrict__ g, const float* __restrict__ B,
                            float* __restrict__ scale, float* __restrict__ shift,
                            float invCount, int CO)
{
    int t = threadIdx.x;
    if (t < CO){
        float mu = sum[t] * invCount;
        float var = fmaf(-mu, mu, sq[t] * invCount);
        float sc = g[t] * rsqrtf(var + 1e-5f);
        scale[t] = sc;
        shift[t] = fmaf(-mu, sc, B[t]);
    }
}

// ---------- encoder layer 2 (fp32, 64 rows/block — NODE encoder) ----------
template<bool BF>
__global__ __launch_bounds__(256) void enc2_kernel(
    void* __restrict__ iov, const float* __restrict__ W, const float* __restrict__ bias,
    const float* __restrict__ scale, const float* __restrict__ shift, int rows)
{
    __shared__ __align__(16) float At[64][68];
    __shared__ __align__(16) float Wl[64][64];
    const int tid = threadIdx.x;
    const int base = blockIdx.x * 64;
    for (int i = tid; i < 4096; i += 256) Wl[i >> 6][i & 63] = W[i];
    for (int i4 = tid; i4 < 1024; i4 += 256){
        int r = i4 >> 4, kc = i4 & 15;
        int gr = base + r;
        float4 v = {0.f, 0.f, 0.f, 0.f};
        if (gr < rows){
            if (BF){
                ushort4 s = *(const ushort4*)((const u16*)iov + (long long)gr * 64 + kc * 4);
                v.x = bf2f(s.x); v.y = bf2f(s.y); v.z = bf2f(s.z); v.w = bf2f(s.w);
            } else {
                v = *(const float4*)((const float*)iov + (long long)gr * 64 + kc * 4);
            }
        }
        float4 o;
        o.x = fmaxf(fmaf(v.x, scale[kc*4+0], shift[kc*4+0]), 0.f);
        o.y = fmaxf(fmaf(v.y, scale[kc*4+1], shift[kc*4+1]), 0.f);
        o.z = fmaxf(fmaf(v.z, scale[kc*4+2], shift[kc*4+2]), 0.f);
        o.w = fmaxf(fmaf(v.w, scale[kc*4+3], shift[kc*4+3]), 0.f);
        *(float4*)&At[r][kc * 4] = o;
    }
    __syncthreads();
    const int tx = tid & 15, ty = tid >> 4;
    float acc[4][4];
    #pragma unroll
    for (int i = 0; i < 4; i++){ acc[i][0]=0.f; acc[i][1]=0.f; acc[i][2]=0.f; acc[i][3]=0.f; }
    #pragma unroll 4
    for (int k4 = 0; k4 < 16; k4++){
        float4 b0 = *(const float4*)&Wl[k4 * 4 + 0][tx * 4];
        float4 b1 = *(const float4*)&Wl[k4 * 4 + 1][tx * 4];
        float4 b2 = *(const float4*)&Wl[k4 * 4 + 2][tx * 4];
        float4 b3 = *(const float4*)&Wl[k4 * 4 + 3][tx * 4];
        #pragma unroll
        for (int i = 0; i < 4; i++){
            float4 a = *(const float4*)&At[ty * 4 + i][k4 * 4];
            acc[i][0] = fmaf(a.x, b0.x, acc[i][0]); acc[i][1] = fmaf(a.x, b0.y, acc[i][1]);
            acc[i][2] = fmaf(a.x, b0.z, acc[i][2]); acc[i][3] = fmaf(a.x, b0.w, acc[i][3]);
            acc[i][0] = fmaf(a.y, b1.x, acc[i][0]); acc[i][1] = fmaf(a.y, b1.y, acc[i][1]);
            acc[i][2] = fmaf(a.y, b1.z, acc[i][2]); acc[i][3] = fmaf(a.y, b1.w, acc[i][3]);
            acc[i][0] = fmaf(a.z, b2.x, acc[i][0]); acc[i][1] = fmaf(a.z, b2.y, acc[i][1]);
            acc[i][2] = fmaf(a.z, b2.z, acc[i][2]); acc[i][3] = fmaf(a.z, b2.w, acc[i][3]);
            acc[i][0] = fmaf(a.w, b3.x, acc[i][0]); acc[i][1] = fmaf(a.w, b3.y, acc[i][1]);
            acc[i][2] = fmaf(a.w, b3.z, acc[i][2]); acc[i][3] = fmaf(a.w, b3.w, acc[i][3]);
        }
    }
    float4 bv = *(const float4*)&bias[tx * 4];
    #pragma unroll
    for (int i = 0; i < 4; i++){
        int gr = base + ty * 4 + i;
        if (gr < rows){
            float4 o;
            o.x = acc[i][0] + bv.x; o.y = acc[i][1] + bv.y;
            o.z = acc[i][2] + bv.z; o.w = acc[i][3] + bv.w;
            if (BF){
                ushort4 s;
                s.x = f2bf(o.x); s.y = f2bf(o.y); s.z = f2bf(o.z); s.w = f2bf(o.w);
                *(ushort4*)((u16*)iov + (long long)gr * 64 + tx * 4) = s;
            } else {
                *(float4*)((float*)iov + (long long)gr * 64 + tx * 4) = o;
            }
        }
    }
}

// ---------- Wt prep (edge enc2) ----------
__global__ void wt_prep_kernel(const float* __restrict__ W, u16* __restrict__ wt)
{
    int i = blockIdx.x * 256 + threadIdx.x;
    if (i < 4096){ int k = i >> 6, c = i & 63; wt[c * 64 + k] = f2bf(W[i]); }
}

// ---------- conv weight prep: cW1[L][64][128] -> wt1[L][128c][64k] bf16; cW2[L][128][64] -> wt2[L][64c][128k] ----------
__global__ void cw_prep_kernel(const float* __restrict__ cW1, const float* __restrict__ cW2,
                               u16* __restrict__ wt1, u16* __restrict__ wt2)
{
    int i = blockIdx.x * 256 + threadIdx.x;
    if (i < 32768){
        int l = i >> 13, j = i & 8191;
        int c = j >> 6, k = j & 63;                 // wt1 dst [c:128][k:64]
        wt1[(long long)l * 8192 + c * 64 + k] = f2bf(cW1[(long long)l * 8192 + k * 128 + c]);
    } else if (i < 65536){
        int t = i - 32768;
        int l = t >> 13, j = t & 8191;
        int c = j >> 7, k = j & 127;                // wt2 dst [c:64][k:128]
        wt2[(long long)l * 8192 + c * 128 + k] = f2bf(cW2[(long long)l * 8192 + k * 64 + c]);
    }
}

// ---------- EDGE encoder layer 2 via MFMA (in-place on bf16 e) ----------
__global__ __launch_bounds__(256) void enc2_mfma_kernel(
    u16* __restrict__ e, const u16* __restrict__ wt, const float* __restrict__ bias,
    const float* __restrict__ scale, const float* __restrict__ shift)
{
    __shared__ __align__(16) u16 At[64][72];
    __shared__ __align__(16) u16 Wt[64][72];
    const int tid = threadIdx.x;
    const long long base = (long long)blockIdx.x * 64;
    for (int i = tid; i < 1024; i += 256){
        int c = i >> 4, kc = i & 15;
        *(ushort4*)&Wt[c][kc * 4] = *(const ushort4*)&wt[c * 64 + kc * 4];
    }
    for (int i = tid; i < 1024; i += 256){
        int r = i >> 4, kc = i & 15;
        ushort4 s = *(const ushort4*)&e[(base + r) * 64 + kc * 4];
        float v0 = fmaxf(fmaf(bf2f(s.x), scale[kc*4+0], shift[kc*4+0]), 0.f);
        float v1 = fmaxf(fmaf(bf2f(s.y), scale[kc*4+1], shift[kc*4+1]), 0.f);
        float v2 = fmaxf(fmaf(bf2f(s.z), scale[kc*4+2], shift[kc*4+2]), 0.f);
        float v3 = fmaxf(fmaf(bf2f(s.w), scale[kc*4+3], shift[kc*4+3]), 0.f);
        ushort4 o; o.x = f2bf(v0); o.y = f2bf(v1); o.z = f2bf(v2); o.w = f2bf(v3);
        *(ushort4*)&At[r][kc * 4] = o;
    }
    __syncthreads();
    const int l = tid & 63;
    const int r0 = (tid >> 6) * 16;
    const int lr = l & 15, lk = (l >> 4) * 8;
    f32x4 acc0 = {0.f,0.f,0.f,0.f}, acc1 = {0.f,0.f,0.f,0.f};
    f32x4 acc2 = {0.f,0.f,0.f,0.f}, acc3 = {0.f,0.f,0.f,0.f};
    #pragma unroll
    for (int k0 = 0; k0 < 64; k0 += 32){
        bf16x8 a  = *(const bf16x8*)&At[r0 + lr][k0 + lk];
        bf16x8 b0 = *(const bf16x8*)&Wt[ 0 + lr][k0 + lk];
        bf16x8 b1 = *(const bf16x8*)&Wt[16 + lr][k0 + lk];
        bf16x8 b2 = *(const bf16x8*)&Wt[32 + lr][k0 + lk];
        bf16x8 b3 = *(const bf16x8*)&Wt[48 + lr][k0 + lk];
        acc0 = __builtin_amdgcn_mfma_f32_16x16x32_bf16(a, b0, acc0, 0, 0, 0);
        acc1 = __builtin_amdgcn_mfma_f32_16x16x32_bf16(a, b1, acc1, 0, 0, 0);
        acc2 = __builtin_amdgcn_mfma_f32_16x16x32_bf16(a, b2, acc2, 0, 0, 0);
        acc3 = __builtin_amdgcn_mfma_f32_16x16x32_bf16(a, b3, acc3, 0, 0, 0);
    }
    const int orow = r0 + (l >> 4) * 4;
    const float bb0 = bias[ 0 + lr], bb1 = bias[16 + lr];
    const float bb2 = bias[32 + lr], bb3 = bias[48 + lr];
    #pragma unroll
    for (int r = 0; r < 4; r++){
        long long rb = (base + orow + r) * 64;
        e[rb +  0 + lr] = f2bf(acc0[r] + bb0);
        e[rb + 16 + lr] = f2bf(acc1[r] + bb1);
        e[rb + 32 + lr] = f2bf(acc2[r] + bb2);
        e[rb + 48 + lr] = f2bf(acc3[r] + bb3);
    }
}

// ---------- r = relu(LayerNorm(h)) ----------
__global__ __launch_bounds__(256) void ln_relu_kernel(
    const float* __restrict__ h, float* __restrict__ r,
    const float* __restrict__ g, const float* __restrict__ b, int rows)
{
    int tid = blockIdx.x * 256 + threadIdx.x;
    int row = tid >> 4, fc = tid & 15;
    if (row >= rows) return;
    float4 v = *(const float4*)&h[(long long)row * 64 + fc * 4];
    float s = v.x + v.y + v.z + v.w;
    float q = v.x*v.x + v.y*v.y + v.z*v.z + v.w*v.w;
    #pragma unroll
    for (int m = 1; m < 16; m <<= 1){ s += __shfl_xor(s, m, 64); q += __shfl_xor(q, m, 64); }
    float mu = s * (1.f / 64.f);
    float var = fmaf(-mu, mu, q * (1.f / 64.f));
    float rs = rsqrtf(var + 1e-5f);
    float4 gv = *(const float4*)&g[fc * 4];
    float4 bv = *(const float4*)&b[fc * 4];
    float4 o;
    o.x = fmaxf(fmaf((v.x - mu) * rs, gv.x, bv.x), 0.f);
    o.y = fmaxf(fmaf((v.y - mu) * rs, gv.y, bv.y), 0.f);
    o.z = fmaxf(fmaf((v.z - mu) * rs, gv.z, bv.z), 0.f);
    o.w = fmaxf(fmaf((v.w - mu) * rs, gv.w, bv.w), 0.f);
    *(float4*)&r[(long long)row * 64 + fc * 4] = o;
}

// ---------- CSR build ----------
__global__ __launch_bounds__(256) void hist_kernel(
    const int* __restrict__ dst, int* __restrict__ cnt)
{
    int eidx = blockIdx.x * 256 + threadIdx.x;
    if (eidx < NE) atomicAdd(&cnt[dst[eidx]], 1);
}

__global__ __launch_bounds__(1024) void scan1_kernel(
    const int* __restrict__ cnt, int* __restrict__ rowptr, int* __restrict__ bsum, int n)
{
    __shared__ int buf[1024];
    int tid = threadIdx.x;
    int gid = blockIdx.x * 1024 + tid;
    int v = (gid < n) ? cnt[gid] : 0;
    buf[tid] = v;
    __syncthreads();
    for (int off = 1; off < 1024; off <<= 1){
        int add = (tid >= off) ? buf[tid - off] : 0;
        __syncthreads();
        buf[tid] += add;
        __syncthreads();
    }
    if (gid < n) rowptr[gid] = buf[tid] - v;
    if (tid == 1023) bsum[blockIdx.x] = buf[1023];
}

__global__ void scan2_kernel(int* __restrict__ bsum, int B)
{
    int lane = threadIdx.x;
    int v = (lane < B) ? bsum[lane] : 0;
    int orig = v;
    #pragma unroll
    for (int off = 1; off < 64; off <<= 1){
        int u = __shfl_up(v, off, 64);
        if (lane >= off) v += u;
    }
    if (lane < B) bsum[lane] = v - orig;
}

__global__ __launch_bounds__(1024) void scan3_kernel(
    int* __restrict__ rowptr, const int* __restrict__ bsum, int n)
{
    int gid = blockIdx.x * 1024 + threadIdx.x;
    if (gid < n) rowptr[gid] += bsum[blockIdx.x];
    if (gid == 0) rowptr[n] = NE;
}

__global__ __launch_bounds__(256) void scatter_kernel(
    const int* __restrict__ src, const int* __restrict__ dst,
    int* __restrict__ cursor, int* __restrict__ perm, int* __restrict__ ssrc)
{
    int eidx = blockIdx.x * 256 + threadIdx.x;
    if (eidx >= NE) return;
    int pos = atomicAdd(&cursor[dst[eidx]], 1);
    perm[pos] = eidx;
    ssrc[pos] = src[eidx];
}

// ---------- per-node aggregation: one wave per node, lane = feature (max-free softmax) ----------
__global__ __launch_bounds__(256) void aggr_kernel(
    const u16* __restrict__ e, const float* __restrict__ xn,
    const int* __restrict__ ssrc,
    const int* __restrict__ rowptr, float* __restrict__ aggr,
    const float* __restrict__ tptr, int rows)
{
    int node = (blockIdx.x * 256 + threadIdx.x) >> 6;
    int lane = threadIdx.x & 63;
    if (node >= rows) return;
    const float tl = (*tptr) * 1.44269504088896f;   // t * log2(e)
    int beg = rowptr[node], end = rowptr[node + 1];
    float den = 0.f, num = 0.f;
    int i = beg;
    for (; i + 4 <= end; i += 4){
        float ev0 = bf2f(e[(long long)(i + 0) * 64 + lane]);
        float ev1 = bf2f(e[(long long)(i + 1) * 64 + lane]);
        float ev2 = bf2f(e[(long long)(i + 2) * 64 + lane]);
        float ev3 = bf2f(e[(long long)(i + 3) * 64 + lane]);
        int s0 = ssrc[i + 0], s1 = ssrc[i + 1], s2 = ssrc[i + 2], s3 = ssrc[i + 3];
        float xv0 = xn[(long long)s0 * 64 + lane];
        float xv1 = xn[(long long)s1 * 64 + lane];
        float xv2 = xn[(long long)s2 * 64 + lane];
        float xv3 = xn[(long long)s3 * 64 + lane];
        float msg0 = fmaxf(xv0 + ev0, 0.f) + 1e-7f;
        float msg1 = fmaxf(xv1 + ev1, 0.f) + 1e-7f;
        float msg2 = fmaxf(xv2 + ev2, 0.f) + 1e-7f;
        float msg3 = fmaxf(xv3 + ev3, 0.f) + 1e-7f;
        float w0 = exp2f(tl * msg0);
        float w1 = exp2f(tl * msg1);
        float w2 = exp2f(tl * msg2);
        float w3 = exp2f(tl * msg3);
        den += (w0 + w1) + (w2 + w3);
        num += fmaf(msg0, w0, msg1 * w1) + fmaf(msg2, w2, msg3 * w3);
    }
    for (; i < end; ++i){
        float ev = bf2f(e[(long long)i * 64 + lane]);
        int s = ssrc[i];
        float xv = xn[(long long)s * 64 + lane];
        float msg = fmaxf(xv + ev, 0.f) + 1e-7f;
        float w = exp2f(tl * msg);
        den += w;
        num = fmaf(msg, w, num);
    }
    aggr[(long long)node * 64 + lane] = num / (den + 1e-16f);
}

// ---------- conv node update via MFMA: a = aggr+rin (bf16); h(+)= relu(LN(a@W1+b1))@W2+b2 ----------
// 64 rows/block, 4 waves. GEMM1: [64,64]@W1t[128c,64k]; GEMM2: [64,128]@W2t[64c,128k].
// Fragment layouts identical to enc2_mfma (HW-verified R12).
__global__ __launch_bounds__(256) void conv_mlp_mfma_kernel(
    const float* __restrict__ rin, const float* __restrict__ aggr,
    float* __restrict__ h,
    const u16* __restrict__ w1g, const float* __restrict__ b1,
    const float* __restrict__ g, const float* __restrict__ B,
    const u16* __restrict__ w2g, const float* __restrict__ b2,
    int addToH, int rows)
{
    // poolA holds At[64][72] + W1t[128][72] in phase 1-2; W2t[64][136] overlays it in phase 3+.
    __shared__ __align__(16) u16 poolA[64 * 72 + 128 * 72];
    __shared__ __align__(16) u16 Hsb[64][136];
    __shared__ float lred[128];
    __shared__ float lmu[64], lrs[64];
    u16 (*At)[72]   = (u16(*)[72])poolA;
    u16 (*W1t)[72]  = (u16(*)[72])(poolA + 64 * 72);
    u16 (*W2t)[136] = (u16(*)[136])poolA;

    const int tid = threadIdx.x;
    const int base = blockIdx.x * 64;
    // phase 1: stage At (bf16 of aggr+rin) + W1t; zero lred
    for (int i4 = tid; i4 < 1024; i4 += 256){
        int r = i4 >> 4, kc = i4 & 15;
        int gr = base + r;
        float4 v = {0.f, 0.f, 0.f, 0.f};
        if (gr < rows){
            long long idx = (long long)gr * 64 + kc * 4;
            float4 av = *(const float4*)&aggr[idx];
            float4 rv = *(const float4*)&rin[idx];
            v.x = av.x + rv.x; v.y = av.y + rv.y; v.z = av.z + rv.z; v.w = av.w + rv.w;
        }
        ushort4 o; o.x = f2bf(v.x); o.y = f2bf(v.y); o.z = f2bf(v.z); o.w = f2bf(v.w);
        *(ushort4*)&At[r][kc * 4] = o;
    }
    for (int i4 = tid; i4 < 2048; i4 += 256){
        int c = i4 >> 4, kc = i4 & 15;
        *(ushort4*)&W1t[c][kc * 4] = *(const ushort4*)&w1g[c * 64 + kc * 4];
    }
    if (tid < 128) lred[tid] = 0.f;
    __syncthreads();

    const int l = tid & 63;
    const int r0 = (tid >> 6) * 16;
    const int lr = l & 15, lk = (l >> 4) * 8;
    const int orow = r0 + (l >> 4) * 4;

    // phase 2: GEMM1 -> Hsb (bf16, pre-LN, bias added)
    {
        f32x4 acc[8];
        #pragma unroll
        for (int ct = 0; ct < 8; ct++) acc[ct] = (f32x4){0.f,0.f,0.f,0.f};
        #pragma unroll
        for (int k0 = 0; k0 < 64; k0 += 32){
            bf16x8 a = *(const bf16x8*)&At[r0 + lr][k0 + lk];
            #pragma unroll
            for (int ct = 0; ct < 8; ct++){
                bf16x8 b = *(const bf16x8*)&W1t[ct * 16 + lr][k0 + lk];
                acc[ct] = __builtin_amdgcn_mfma_f32_16x16x32_bf16(a, b, acc[ct], 0, 0, 0);
            }
        }
        #pragma unroll
        for (int ct = 0; ct < 8; ct++){
            int col = ct * 16 + lr;
            float bb = b1[col];
            #pragma unroll
            for (int r = 0; r < 4; r++)
                Hsb[orow + r][col] = f2bf(acc[ct][r] + bb);
        }
    }
    __syncthreads();   // all poolA reads + Hsb writes done

    // phase 3: LN stats (read Hsb) + stage W2t into poolA
    {
        int row = tid & 63, seg = tid >> 6;
        float s = 0.f, q = 0.f;
        #pragma unroll
        for (int j4 = 0; j4 < 8; j4++){
            ushort4 hv = *(const ushort4*)&Hsb[row][seg * 32 + j4 * 4];
            float v0 = bf2f(hv.x), v1 = bf2f(hv.y), v2 = bf2f(hv.z), v3 = bf2f(hv.w);
            s += (v0 + v1) + (v2 + v3);
            q += fmaf(v0, v0, v1 * v1) + fmaf(v2, v2, v3 * v3);
        }
        atomicAdd(&lred[row], s);
        atomicAdd(&lred[64 + row], q);
        for (int i4 = tid; i4 < 2048; i4 += 256){
            int c = i4 >> 5, kc = i4 & 31;
            *(ushort4*)&W2t[c][kc * 4] = *(const ushort4*)&w2g[c * 128 + kc * 4];
        }
    }
    __syncthreads();
    if (tid < 64){
        float mu = lred[tid] * (1.f / 128.f);
        float var = fmaf(-mu, mu, lred[64 + tid] * (1.f / 128.f));
        lmu[tid] = mu; lrs[tid] = rsqrtf(var + 1e-5f);
    }
    __syncthreads();

    // phase 4: LN apply + relu in place (bf16)
    {
        int row = tid & 63, seg = tid >> 6;
        float mu = lmu[row], rs = lrs[row];
        #pragma unroll
        for (int j4 = 0; j4 < 8; j4++){
            int k = seg * 32 + j4 * 4;
            ushort4 hv = *(const ushort4*)&Hsb[row][k];
            float4 gv = *(const float4*)&g[k];
            float4 Bv = *(const float4*)&B[k];
            float v0 = fmaxf(fmaf((bf2f(hv.x) - mu) * rs, gv.x, Bv.x), 0.f);
            float v1 = fmaxf(fmaf((bf2f(hv.y) - mu) * rs, gv.y, Bv.y), 0.f);
            float v2 = fmaxf(fmaf((bf2f(hv.z) - mu) * rs, gv.z, Bv.z), 0.f);
            float v3 = fmaxf(fmaf((bf2f(hv.w) - mu) * rs, gv.w, Bv.w), 0.f);
            ushort4 o; o.x = f2bf(v0); o.y = f2bf(v1); o.z = f2bf(v2); o.w = f2bf(v3);
            *(ushort4*)&Hsb[row][k] = o;
        }
    }
    __syncthreads();

    // phase 5: GEMM2 -> h (+ residual)
    {
        f32x4 acc[4];
        #pragma unroll
        for (int ct = 0; ct < 4; ct++) acc[ct] = (f32x4){0.f,0.f,0.f,0.f};
        #pragma unroll
        for (int k0 = 0; k0 < 128; k0 += 32){
            bf16x8 a = *(const bf16x8*)&Hsb[r0 + lr][k0 + lk];
            #pragma unroll
            for (int ct = 0; ct < 4; ct++){
                bf16x8 b = *(const bf16x8*)&W2t[ct * 16 + lr][k0 + lk];
                acc[ct] = __builtin_amdgcn_mfma_f32_16x16x32_bf16(a, b, acc[ct], 0, 0, 0);
            }
        }
        #pragma unroll
        for (int ct = 0; ct < 4; ct++){
            int col = ct * 16 + lr;
            float bb = b2[col];
            #pragma unroll
            for (int r = 0; r < 4; r++){
                int gr = base + orow + r;
                if (gr < rows){
                    long long idx = (long long)gr * 64 + col;
                    float v = acc[ct][r] + bb;
                    if (addToH) v += h[idx];
                    h[idx] = v;
                }
            }
        }
    }
}

// ---------- out MLP stage 1: 64 rows/block, 4 lanes/row x 8 cols ----------
__global__ __launch_bounds__(256) void out1_kernel(
    const float* __restrict__ A, const float* __restrict__ W, const float* __restrict__ bias,
    float* __restrict__ out, float* __restrict__ stSum, float* __restrict__ stSq, int rows)
{
    __shared__ __align__(16) float At[64][68];
    __shared__ __align__(16) float Wl[64][32];
    __shared__ float ssum[32], ssq[32];
    const int tid = threadIdx.x;
    const int base = blockIdx.x * 64;
    for (int i = tid; i < 2048; i += 256) Wl[i >> 5][i & 31] = W[i];
    if (tid < 32){ ssum[tid] = 0.f; ssq[tid] = 0.f; }
    for (int i4 = tid; i4 < 1024; i4 += 256){
        int r = i4 >> 4, kc = i4 & 15;
        int gr = base + r;
        float4 v = {0.f, 0.f, 0.f, 0.f};
        if (gr < rows) v = *(const float4*)&A[(long long)gr * 64 + kc * 4];
        *(float4*)&At[r][kc * 4] = v;
    }
    __syncthreads();
    const int row = tid >> 2, lane = tid & 3;
    const int gr = base + row;
    float acc[8];
    #pragma unroll
    for (int j = 0; j < 8; j++) acc[j] = bias[lane * 8 + j];
    #pragma unroll 4
    for (int k4 = 0; k4 < 16; k4++){
        float4 a = *(const float4*)&At[row][k4 * 4];
        float av[4] = {a.x, a.y, a.z, a.w};
        #pragma unroll
        for (int j = 0; j < 4; j++){
            float4 w0 = *(const float4*)&Wl[k4 * 4 + j][lane * 8];
            float4 w1 = *(const float4*)&Wl[k4 * 4 + j][lane * 8 + 4];
            acc[0] = fmaf(av[j], w0.x, acc[0]); acc[1] = fmaf(av[j], w0.y, acc[1]);
            acc[2] = fmaf(av[j], w0.z, acc[2]); acc[3] = fmaf(av[j], w0.w, acc[3]);
            acc[4] = fmaf(av[j], w1.x, acc[4]); acc[5] = fmaf(av[j], w1.y, acc[5]);
            acc[6] = fmaf(av[j], w1.z, acc[6]); acc[7] = fmaf(av[j], w1.w, acc[7]);
        }
    }
    if (gr < rows){
        float4 o0 = {acc[0], acc[1], acc[2], acc[3]};
        float4 o1 = {acc[4], acc[5], acc[6], acc[7]};
        *(float4*)&out[(long long)gr * 32 + lane * 8]     = o0;
        *(float4*)&out[(long long)gr * 32 + lane * 8 + 4] = o1;
        #pragma unroll
        for (int j = 0; j < 8; j++){
            atomicAdd(&ssum[lane * 8 + j], acc[j]);
            atomicAdd(&ssq [lane * 8 + j], acc[j] * acc[j]);
        }
    }
    __syncthreads();
    if (tid < 32){ atomicAdd(&stSum[tid], ssum[tid]); atomicAdd(&stSq[tid], ssq[tid]); }
}

// ---------- out MLP stage 2: 64 rows/block, 4 lanes/row x 4 cols; BN applied at staging ----------
__global__ __launch_bounds__(256) void out2_kernel(
    const float* __restrict__ A, const float* __restrict__ W, const float* __restrict__ bias,
    float* __restrict__ out, const float* __restrict__ sc, const float* __restrict__ sh,
    float* __restrict__ stSum, float* __restrict__ stSq, int rows)
{
    __shared__ __align__(16) float At[64][36];
    __shared__ __align__(16) float Wl[32][16];
    __shared__ float ssum[16], ssq[16];
    const int tid = threadIdx.x;
    const int base = blockIdx.x * 64;
    for (int i = tid; i < 512; i += 256) Wl[i >> 4][i & 15] = W[i];
    if (tid < 16){ ssum[tid] = 0.f; ssq[tid] = 0.f; }
    for (int i4 = tid; i4 < 512; i4 += 256){
        int r = i4 >> 3, kc = i4 & 7;
        int gr = base + r;
        float4 v = {0.f, 0.f, 0.f, 0.f};
        if (gr < rows) v = *(const float4*)&A[(long long)gr * 32 + kc * 4];
        float4 o;
        o.x = fmaxf(fmaf(v.x, sc[kc*4+0], sh[kc*4+0]), 0.f);
        o.y = fmaxf(fmaf(v.y, sc[kc*4+1], sh[kc*4+1]), 0.f);
        o.z = fmaxf(fmaf(v.z, sc[kc*4+2], sh[kc*4+2]), 0.f);
        o.w = fmaxf(fmaf(v.w, sc[kc*4+3], sh[kc*4+3]), 0.f);
        *(float4*)&At[r][kc * 4] = o;
    }
    __syncthreads();
    const int row = tid >> 2, lane = tid & 3;
    const int gr = base + row;
    float acc[4];
    #pragma unroll
    for (int j = 0; j < 4; j++) acc[j] = bias[lane * 4 + j];
    #pragma unroll 2
    for (int k4 = 0; k4 < 8; k4++){
        float4 a = *(const float4*)&At[row][k4 * 4];
        float av[4] = {a.x, a.y, a.z, a.w};
        #pragma unroll
        for (int j = 0; j < 4; j++){
            float4 w = *(const float4*)&Wl[k4 * 4 + j][lane * 4];
            acc[0] = fmaf(av[j], w.x, acc[0]); acc[1] = fmaf(av[j], w.y, acc[1]);
            acc[2] = fmaf(av[j], w.z, acc[2]); acc[3] = fmaf(av[j], w.w, acc[3]);
        }
    }
    if (gr < rows){
        float4 o = {acc[0], acc[1], acc[2], acc[3]};
        *(float4*)&out[(long long)gr * 16 + lane * 4] = o;
        #pragma unroll
        for (int j = 0; j < 4; j++){
            atomicAdd(&ssum[lane * 4 + j], acc[j]);
            atomicAdd(&ssq [lane * 4 + j], acc[j] * acc[j]);
        }
    }
    __syncthreads();
    if (tid < 16){ atomicAdd(&stSum[tid], ssum[tid]); atomicAdd(&stSq[tid], ssq[tid]); }
}

// ---------- out MLP stage 3 ----------
__global__ __launch_bounds__(256) void out3_kernel(
    const float* __restrict__ A, const float* __restrict__ W, const float* __restrict__ bias,
    const float* __restrict__ sc, const float* __restrict__ sh,
    float* __restrict__ out, int rows)
{
    int row = blockIdx.x * 256 + threadIdx.x;
    if (row >= rows) return;
    float o0 = bias[0], o1 = bias[1];
    #pragma unroll
    for (int k = 0; k < 16; k++){
        float a = fmaxf(fmaf(A[(long long)row * 16 + k], sc[k], sh[k]), 0.f);
        o0 = fmaf(a, W[k * 2 + 0], o0);
        o1 = fmaf(a, W[k * 2 + 1], o1);
    }
    out[(long long)row * 2 + 0] = o0;
    out[(long long)row * 2 + 1] = o1;
}

extern "C" void kernel_launch(void* const* d_in, const int* in_sizes, int n_in,
                              void* d_out, int out_size, void* d_ws, size_t ws_size,
                              hipStream_t stream)
{
    (void)in_sizes; (void)n_in; (void)out_size;
    if (ws_size < WS_NEED) return;

    const float* x    = (const float*)d_in[0];
    const float* ea   = (const float*)d_in[1];
    const int*   eidx = (const int*)  d_in[2];
    const float* nW1  = (const float*)d_in[3];
    const float* nb1  = (const float*)d_in[4];
    const float* ng1  = (const float*)d_in[5];
    const float* nB1  = (const float*)d_in[6];
    const float* nW2  = (const float*)d_in[7];
    const float* nb2  = (const float*)d_in[8];
    const float* eW1  = (const float*)d_in[9];
    const float* eb1  = (const float*)d_in[10];
    const float* eg1  = (const float*)d_in[11];
    const float* eB1  = (const float*)d_in[12];
    const float* eW2  = (const float*)d_in[13];
    const float* eb2  = (const float*)d_in[14];
    const float* lng  = (const float*)d_in[15];
    const float* lnb  = (const float*)d_in[16];
    const float* cW1  = (const float*)d_in[17];
    const float* cb1  = (const float*)d_in[18];
    const float* cg   = (const float*)d_in[19];
    const float* cB   = (const float*)d_in[20];
    const float* cW2  = (const float*)d_in[21];
    const float* cb2  = (const float*)d_in[22];
    const float* ct   = (const float*)d_in[23];
    const float* oW1  = (const float*)d_in[24];
    const float* ob1  = (const float*)d_in[25];
    const float* og1  = (const float*)d_in[26];
    const float* oB1  = (const float*)d_in[27];
    const float* oW2  = (const float*)d_in[28];
    const float* ob2  = (const float*)d_in[29];
    const float* og2  = (const float*)d_in[30];
    const float* oB2  = (const float*)d_in[31];
    const float* oW3  = (const float*)d_in[32];
    const float* ob3  = (const float*)d_in[33];

    float* ws = (float*)d_ws;
    u16*   e    = (u16*)(ws + OFF_E);
    float* h    = ws + OFF_H;
    float* r    = ws + OFF_R;
    float* aggr = ws + OFF_AG;
    int*   csr  = (int*)(ws + OFF_CSR);
    int*   rowptr = csr + CSR_ROWPTR;
    int*   cnt    = csr + CSR_CNT;
    int*   perm   = csr + CSR_PERM;
    int*   ssrc   = csr + CSR_SSRC;
    int*   bsum   = csr + CSR_BSUM;
    u16*   wt     = (u16*)(csr + CSR_WT);
    u16*   wt1    = (u16*)(csr + CSR_WT1);
    u16*   wt2    = (u16*)(csr + CSR_WT2);
    float* stPart = (float*)(csr + CSR_SPART);
    float* t1   = ws + OFF_AG;                 // overlay (aggr dead after convs)
    float* t2   = ws + OFF_AG + 1600000;
    float* st   = ws + OFF_ST;
    float* sumA = st;        float* sqA = st + 128;
    float* scA  = st + 256;  float* shA = st + 384;
    float* sumB = st + 512;  float* sqB = st + 640;
    float* scB  = st + 768;  float* shB = st + 896;

    const int* src = eidx;
    const int* dst = eidx + NE;
    const int SCAN_B = (NN + 1023) / 1024;   // 49

    // ---- CSR build (once; depends only on edge_index) ----
    (void)hipMemsetAsync(cnt, 0, NN * sizeof(int), stream);
    hist_kernel<<<(NE + 255) / 256, 256, 0, stream>>>(dst, cnt);
    scan1_kernel<<<SCAN_B, 1024, 0, stream>>>(cnt, rowptr, bsum, NN);
    scan2_kernel<<<1, 64, 0, stream>>>(bsum, SCAN_B);
    scan3_kernel<<<SCAN_B, 1024, 0, stream>>>(rowptr, bsum, NN);
    (void)hipMemcpyAsync(cnt, rowptr, NN * sizeof(int), hipMemcpyDeviceToDevice, stream);
    scatter_kernel<<<(NE + 255) / 256, 256, 0, stream>>>(src, dst, cnt, perm, ssrc);
    wt_prep_kernel<<<16, 256, 0, stream>>>(eW2, wt);
    cw_prep_kernel<<<256, 256, 0, stream>>>(cW1, cW2, wt1, wt2);

    // ---- node encoder (fp32 h) ----
    (void)hipMemsetAsync(st, 0, 256 * sizeof(float), stream);
    enc1_kernel<16, false><<<1024, 256, 0, stream>>>(x, nW1, nb1, h, nullptr, stPart, NN, (NN + 63) / 64);
    stat_reduce_par<<<64, 128, 0, stream>>>(stPart, 1024, sumA, sqA);
    bn_finalize<<<1, 128, 0, stream>>>(sumA, sqA, ng1, nB1, scA, shA, 1.f / NN, 64);
    enc2_kernel<false><<<(NN + 63) / 64, 256, 0, stream>>>(h, nW2, nb2, scA, shA, NN);
    // ---- edge encoder (bf16 e in CSR-permuted order; layer 2 via MFMA) ----
    (void)hipMemsetAsync(st, 0, 256 * sizeof(float), stream);
    enc1_kernel<8, true><<<2048, 256, 0, stream>>>(ea, eW1, eb1, e, perm, stPart, NE, NE / 64);
    stat_reduce_par<<<128, 128, 0, stream>>>(stPart, 2048, sumA, sqA);
    bn_finalize<<<1, 128, 0, stream>>>(sumA, sqA, eg1, eB1, scA, shA, 1.f / NE, 64);
    enc2_mfma_kernel<<<NE / 64, 256, 0, stream>>>(e, wt, eb2, scA, shA);

    // ---- 4 GENConv layers ----
    for (int l = 0; l < 4; l++){
        const float* rin = (l == 0) ? h : r;
        if (l > 0)
            ln_relu_kernel<<<(NN * 16) / 256, 256, 0, stream>>>(h, r, lng + l * 64, lnb + l * 64, NN);
        aggr_kernel<<<(NN * 64 + 255) / 256, 256, 0, stream>>>(
            e, rin, ssrc, rowptr, aggr, ct + l, NN);
        conv_mlp_mfma_kernel<<<(NN + 63) / 64, 256, 0, stream>>>(
            rin, aggr, h,
            wt1 + (long long)l * 8192, cb1 + l * 128, cg + l * 128, cB + l * 128,
            wt2 + (long long)l * 8192, cb2 + l * 64, (l > 0) ? 1 : 0, NN);
    }

    // ---- out MLP ----
    (void)hipMemsetAsync(st, 0, 1024 * sizeof(float), stream);
    out1_kernel<<<(NN + 63) / 64, 256, 0, stream>>>(h, oW1, ob1, t1, sumA, sqA, NN);
    bn_finalize<<<1, 128, 0, stream>>>(sumA, sqA, og1, oB1, scA, shA, 1.f / NN, 32);
    out2_kernel<<<(NN + 63) / 64, 256, 0, stream>>>(t1, oW2, ob2, t2, scA, shA, sumB, sqB, NN);
    bn_finalize<<<1, 128, 0, stream>>>(sumB, sqB, og2, oB2, scB, shB, 1.f / NN, 16);
    out3_kernel<<<(NN + 255) / 256, 256, 0, stream>>>(t2, oW3, ob3, scB, shB, (float*)d_out, NN);
}